// Round 5
// baseline (494.952 us; speedup 1.0000x reference)
//
#include <hip/hip_runtime.h>

// clip_nce: Q=16384 queries, V=4096 videos, scores [Q,V] fp32, labels [Q] int.
// R9 -> R10: restore nt loads (R9 A/B: plain loads cost +26us — nt protects the
// cache path from the 1GiB poison-writeback thrash). ONE new lever: strip ALL
// cross-lane + atomic work out of the streaming loop. Mechanism: vmem retires
// in-order per wave, so the in-loop lane-0 global_atomic (L2-home roundtrip)
// sits in the load queue and every vmcnt wait for load data also waits behind
// it. Row partials -> 8 statically-indexed registers (nested row x quarter full
// unroll, all indices compile-time); the 8x(6-shfl + atomic) reduce runs ONCE
// after the stream. Unlike R7's failed rp[32] (32 accum regs starved the load
// buffers, VGPR=40), this costs 24 accum regs total.

#define QN 16384
#define VN 4096
#define NB 2048
#define TB 256
#define F4_PER_BLOCK 8192                 // 128 KB contiguous per block (8 rows)

typedef float f32x4 __attribute__((ext_vector_type(4)));

// workspace layout in floats (~33.5 MiB):
#define COLCOMP_OFF 0                     // NB*4096 column partials (full row per block)
#define ROWSUM_OFF  (NB * 4096)           // QN: sum exp per row (global atomics)
#define NOMSUM_OFF  (ROWSUM_OFF + QN)     // VN: sum exp(s) per label
#define COLSUM_OFF  (NOMSUM_OFF + VN)     // VN: column exp-sums (natural order)
#define ACC_OFF     (COLSUM_OFF + VN)     // [0]=sum log rowsum, [1]=sum s
#define ZERO_FLOATS (QN + VN + VN + 8)    // rowsum + nomsum + colsum + acc

// 16384 label gathers (one cache line each) + nomsum + sum(s)
__global__ __launch_bounds__(256) void gather_pass(const float* __restrict__ scores,
                                                   const int* __restrict__ labels,
                                                   float* __restrict__ ws) {
    float* nomsum = ws + NOMSUM_OFF;
    float* acc    = ws + ACC_OFF;
    const int i = blockIdx.x * 256 + threadIdx.x;
    const int lab = labels[i];
    const float s = scores[(size_t)i * VN + lab];
    unsafeAtomicAdd(&nomsum[lab], __expf(s));
    float v = s;
#pragma unroll
    for (int off = 32; off >= 1; off >>= 1)
        v += __shfl_down(v, off);
    if ((threadIdx.x & 63) == 0) unsafeAtomicAdd(&acc[1], v);
}

// Contiguous dense sweep, NON-TEMPORAL loads, pure streaming loop.
// Block b sweeps f4 indices [b*8192, (b+1)*8192): row r=b*8+r', quarter q,
// f4 = b*8192 + (r'*4+q)*256 + t; col = q*1024 + t*4 + {0..3}.
// Loop body: load -> 4 exp -> col accum (static c_qj) -> row accum (static r_r').
// NO shfl, NO atomics, NO LDS until after the last load.
__global__ __launch_bounds__(256, 8) void main_pass(const float* __restrict__ scores,
                                                    float* __restrict__ ws) {
    float* rowsum  = ws + ROWSUM_OFF;
    float* colcomp = ws + COLCOMP_OFF;
    const int tid  = threadIdx.x;
    const int b    = blockIdx.x;
    const int lane = tid & 63;
    const f32x4* sp = reinterpret_cast<const f32x4*>(scores);
    const size_t base = (size_t)b * F4_PER_BLOCK + tid;

    float c00=0.f,c01=0.f,c02=0.f,c03=0.f;   // q=0
    float c10=0.f,c11=0.f,c12=0.f,c13=0.f;   // q=1
    float c20=0.f,c21=0.f,c22=0.f,c23=0.f;   // q=2
    float c30=0.f,c31=0.f,c32=0.f,c33=0.f;   // q=3
    float r[8] = {0.f,0.f,0.f,0.f,0.f,0.f,0.f,0.f};  // per-row partials

#pragma unroll
    for (int rr = 0; rr < 8; ++rr) {         // row within block — static
#pragma unroll
        for (int q = 0; q < 4; ++q) {        // quarter-row — static
            f32x4 x = __builtin_nontemporal_load(&sp[base + (rr * 4 + q) * 256]);
            float e0 = __expf(x.x), e1 = __expf(x.y);
            float e2 = __expf(x.z), e3 = __expf(x.w);
            switch (q) {                     // compile-time
                case 0: c00 += e0; c01 += e1; c02 += e2; c03 += e3; break;
                case 1: c10 += e0; c11 += e1; c12 += e2; c13 += e3; break;
                case 2: c20 += e0; c21 += e1; c22 += e2; c23 += e3; break;
                case 3: c30 += e0; c31 += e1; c32 += e2; c33 += e3; break;
            }
            r[rr] += (e0 + e1) + (e2 + e3);  // static index
        }
    }

    // deferred row reduction: 8 independent 6-shfl chains, then 4 atomics/row.
#pragma unroll
    for (int rr = 0; rr < 8; ++rr) {
        float v = r[rr];
#pragma unroll
        for (int off = 32; off >= 1; off >>= 1)
            v += __shfl_down(v, off);
        if (lane == 0)
            unsafeAtomicAdd(&rowsum[b * 8 + rr], v);
    }

    // col partials: block writes one full 4096-wide row of partials, coalesced.
    // colcomp[b*4096 + q*1024 + t*4 + j] <-> col q*1024 + t*4 + j
    f32x4* cc = reinterpret_cast<f32x4*>(colcomp + (size_t)b * 4096);
    f32x4 o;
    o.x=c00; o.y=c01; o.z=c02; o.w=c03; cc[0 * 256 + tid] = o;
    o.x=c10; o.y=c11; o.z=c12; o.w=c13; cc[1 * 256 + tid] = o;
    o.x=c20; o.y=c21; o.z=c22; o.w=c23; cc[2 * 256 + tid] = o;
    o.x=c30; o.y=c31; o.z=c32; o.w=c33; cc[3 * 256 + tid] = o;
}

// blocks [0,128): colsum from partials (32 MiB read, coalesced).
//   block = mg*16 + cb: b-range mg (8 groups of 256 blocks), col-chunk cb (16 x 256 cols)
// blocks [128,192): sum log rowsum -> acc[0]
__global__ __launch_bounds__(256) void reduce_pass(float* __restrict__ ws) {
    const float* colcomp = ws + COLCOMP_OFF;
    const float* rowsum  = ws + ROWSUM_OFF;
    float* colsum = ws + COLSUM_OFF;
    float* acc    = ws + ACC_OFF;
    const int tid = threadIdx.x;

    if (blockIdx.x < 128) {
        const int mg = blockIdx.x >> 4;          // block-range group 0..7
        const int cb = blockIdx.x & 15;          // 256-col chunk 0..15
        const int c  = cb * 256 + tid;           // column 0..4095
        float sum = 0.0f;
#pragma unroll 4
        for (int m = mg * 256; m < mg * 256 + 256; ++m)
            sum += colcomp[(size_t)m * 4096 + c];
        unsafeAtomicAdd(&colsum[c], sum);
    } else {
        const int idx = (blockIdx.x - 128) * 256 + tid;
        float v = __logf(rowsum[idx]);
#pragma unroll
        for (int off = 32; off >= 1; off >>= 1)
            v += __shfl_down(v, off);
        if ((tid & 63) == 0) unsafeAtomicAdd(&acc[0], v);
    }
}

__global__ __launch_bounds__(256) void final_pass(const float* __restrict__ ws,
                                                  float* __restrict__ out) {
    const float* nomsum = ws + NOMSUM_OFF;
    const float* colsum = ws + COLSUM_OFF;
    const float* acc    = ws + ACC_OFF;
    const int tid = threadIdx.x;

    float local = 0.0f;
    for (int c = tid; c < VN; c += 256)
        local += __logf(colsum[c]) - __logf(nomsum[c]);
#pragma unroll
    for (int off = 32; off >= 1; off >>= 1)
        local += __shfl_down(local, off);
    __shared__ float red[4];
    const int wid = tid >> 6, lane = tid & 63;
    if (lane == 0) red[wid] = local;
    __syncthreads();
    if (tid == 0) {
        const float v2t = (red[0] + red[1]) + (red[2] + red[3]);
        // mean(log rowsum - s) + mean(log colsum - log nomsum)
        out[0] = (acc[0] - acc[1]) * (1.0f / QN) + v2t * (1.0f / VN);
    }
}

extern "C" void kernel_launch(void* const* d_in, const int* in_sizes, int n_in,
                              void* d_out, int out_size, void* d_ws, size_t ws_size,
                              hipStream_t stream) {
    const float* scores = (const float*)d_in[0];
    const int*   labels = (const int*)d_in[1];
    float* ws  = (float*)d_ws;
    float* out = (float*)d_out;

    hipMemsetAsync(ws + ROWSUM_OFF, 0, ZERO_FLOATS * sizeof(float), stream);
    gather_pass<<<QN / 256, 256, 0, stream>>>(scores, labels, ws);
    main_pass<<<NB, TB, 0, stream>>>(scores, ws);
    reduce_pass<<<192, 256, 0, stream>>>(ws);
    final_pass<<<1, 256, 0, stream>>>(ws, out);
}

// Round 6
// 387.386 us; speedup vs baseline: 1.2777x; 1.2777x over previous
//
#include <hip/hip_runtime.h>

// clip_nce: Q=16384 queries, V=4096 videos, scores [Q,V] fp32, labels [Q] int.
// R10 -> R11: REVERT deferred reduction (2-for-2 regression: R7=431, R10=495 vs
// in-loop R5=365, R8=372 -> in-loop shfl+atomic is FROZEN as proven-good).
// Base = R8 (contiguous 128KB/block + nt loads + in-loop reduce).
// ONE lever: NON-TEMPORAL STORES for colcomp. Evidence (R10 counters): main
// WRITE_SIZE=313MB vs 32MB of actual colcomp writes -> ~280MB of harness-poison
// writeback is evicted onto main's critical path by colcomp's write-allocate.
// nt stores don't allocate -> dirty poison stays cached and dies when the next
// iteration's fill overwrites it (harness time, not ours). reduce_pass re-reads
// colcomp via nt loads from HBM (+32MB, ~5us) -- net ~250MB traffic cut.

#define QN 16384
#define VN 4096
#define NB 2048
#define TB 256
#define ITERS 32                          // 8 rows * 4 quarter-rows
#define F4_PER_BLOCK 8192                 // 128 KB contiguous per block

typedef float f32x4 __attribute__((ext_vector_type(4)));

// workspace layout in floats (~33.5 MiB):
#define COLCOMP_OFF 0                     // NB*4096 column partials (full row per block)
#define ROWSUM_OFF  (NB * 4096)           // QN: sum exp per row (global atomics)
#define NOMSUM_OFF  (ROWSUM_OFF + QN)     // VN: sum exp(s) per label
#define COLSUM_OFF  (NOMSUM_OFF + VN)     // VN: column exp-sums (natural order)
#define ACC_OFF     (COLSUM_OFF + VN)     // [0]=sum log rowsum, [1]=sum s
#define ZERO_FLOATS (QN + VN + VN + 8)    // rowsum + nomsum + colsum + acc

// 16384 label gathers (one cache line each) + nomsum + sum(s)
__global__ __launch_bounds__(256) void gather_pass(const float* __restrict__ scores,
                                                   const int* __restrict__ labels,
                                                   float* __restrict__ ws) {
    float* nomsum = ws + NOMSUM_OFF;
    float* acc    = ws + ACC_OFF;
    const int i = blockIdx.x * 256 + threadIdx.x;
    const int lab = labels[i];
    const float s = scores[(size_t)i * VN + lab];
    unsafeAtomicAdd(&nomsum[lab], __expf(s));
    float v = s;
#pragma unroll
    for (int off = 32; off >= 1; off >>= 1)
        v += __shfl_down(v, off);
    if ((threadIdx.x & 63) == 0) unsafeAtomicAdd(&acc[1], v);
}

// Contiguous dense sweep, NON-TEMPORAL loads, in-loop reduce (R8-proven shape).
// Block b sweeps f4 indices [b*8192, (b+1)*8192) in 32 steps of 256 f4 (4 KB).
//   iter k: f4 = b*8192 + k*256 + t
//   row = b*8 + (k>>2); col = (k&3)*1024 + t*4 + {0..3}
__global__ __launch_bounds__(256, 8) void main_pass(const float* __restrict__ scores,
                                                    float* __restrict__ ws) {
    float* rowsum  = ws + ROWSUM_OFF;
    float* colcomp = ws + COLCOMP_OFF;
    const int tid  = threadIdx.x;
    const int b    = blockIdx.x;
    const int lane = tid & 63;
    const f32x4* sp = reinterpret_cast<const f32x4*>(scores);
    const size_t base = (size_t)b * F4_PER_BLOCK + tid;

    float c00=0.f,c01=0.f,c02=0.f,c03=0.f;   // q=0
    float c10=0.f,c11=0.f,c12=0.f,c13=0.f;   // q=1
    float c20=0.f,c21=0.f,c22=0.f,c23=0.f;   // q=2
    float c30=0.f,c31=0.f,c32=0.f,c33=0.f;   // q=3

#pragma unroll 8
    for (int k = 0; k < ITERS; ++k) {
        f32x4 x = __builtin_nontemporal_load(&sp[base + k * 256]);
        float e0 = __expf(x.x), e1 = __expf(x.y);
        float e2 = __expf(x.z), e3 = __expf(x.w);
        // q = k&3 is a compile-time constant inside the unrolled body
        switch (k & 3) {
            case 0: c00 += e0; c01 += e1; c02 += e2; c03 += e3; break;
            case 1: c10 += e0; c11 += e1; c12 += e2; c13 += e3; break;
            case 2: c20 += e0; c21 += e1; c22 += e2; c23 += e3; break;
            case 3: c30 += e0; c31 += e1; c32 += e2; c33 += e3; break;
        }
        float rp = (e0 + e1) + (e2 + e3);
#pragma unroll
        for (int off = 32; off >= 1; off >>= 1)
            rp += __shfl_down(rp, off);
        if (lane == 0)   // 16 atomics per row address total (4 waves x 4 quarter-iters)
            unsafeAtomicAdd(&rowsum[b * 8 + (k >> 2)], rp);
    }

    // col partials: one full 4096-wide row of partials, coalesced, NON-TEMPORAL
    // (write-through, no allocate -> doesn't evict the fill's dirty poison).
    // colcomp[b*4096 + q*1024 + t*4 + j] <-> col q*1024 + t*4 + j
    f32x4* cc = reinterpret_cast<f32x4*>(colcomp + (size_t)b * 4096);
    f32x4 o;
    o.x=c00; o.y=c01; o.z=c02; o.w=c03; __builtin_nontemporal_store(o, &cc[0 * 256 + tid]);
    o.x=c10; o.y=c11; o.z=c12; o.w=c13; __builtin_nontemporal_store(o, &cc[1 * 256 + tid]);
    o.x=c20; o.y=c21; o.z=c22; o.w=c23; __builtin_nontemporal_store(o, &cc[2 * 256 + tid]);
    o.x=c30; o.y=c31; o.z=c32; o.w=c33; __builtin_nontemporal_store(o, &cc[3 * 256 + tid]);
}

// blocks [0,128): colsum from partials (32 MiB nt read, coalesced).
//   block = mg*16 + cb: b-range mg (8 groups of 256 blocks), col-chunk cb (16 x 256 cols)
// blocks [128,192): sum log rowsum -> acc[0]
__global__ __launch_bounds__(256) void reduce_pass(float* __restrict__ ws) {
    const float* colcomp = ws + COLCOMP_OFF;
    const float* rowsum  = ws + ROWSUM_OFF;
    float* colsum = ws + COLSUM_OFF;
    float* acc    = ws + ACC_OFF;
    const int tid = threadIdx.x;

    if (blockIdx.x < 128) {
        const int mg = blockIdx.x >> 4;          // block-range group 0..7
        const int cb = blockIdx.x & 15;          // 256-col chunk 0..15
        const int c  = cb * 256 + tid;           // column 0..4095
        float sum = 0.0f;
#pragma unroll 4
        for (int m = mg * 256; m < mg * 256 + 256; ++m)
            sum += __builtin_nontemporal_load(&colcomp[(size_t)m * 4096 + c]);
        unsafeAtomicAdd(&colsum[c], sum);
    } else {
        const int idx = (blockIdx.x - 128) * 256 + tid;
        float v = __logf(rowsum[idx]);
#pragma unroll
        for (int off = 32; off >= 1; off >>= 1)
            v += __shfl_down(v, off);
        if ((tid & 63) == 0) unsafeAtomicAdd(&acc[0], v);
    }
}

__global__ __launch_bounds__(256) void final_pass(const float* __restrict__ ws,
                                                  float* __restrict__ out) {
    const float* nomsum = ws + NOMSUM_OFF;
    const float* colsum = ws + COLSUM_OFF;
    const float* acc    = ws + ACC_OFF;
    const int tid = threadIdx.x;

    float local = 0.0f;
    for (int c = tid; c < VN; c += 256)
        local += __logf(colsum[c]) - __logf(nomsum[c]);
#pragma unroll
    for (int off = 32; off >= 1; off >>= 1)
        local += __shfl_down(local, off);
    __shared__ float red[4];
    const int wid = tid >> 6, lane = tid & 63;
    if (lane == 0) red[wid] = local;
    __syncthreads();
    if (tid == 0) {
        const float v2t = (red[0] + red[1]) + (red[2] + red[3]);
        // mean(log rowsum - s) + mean(log colsum - log nomsum)
        out[0] = (acc[0] - acc[1]) * (1.0f / QN) + v2t * (1.0f / VN);
    }
}

extern "C" void kernel_launch(void* const* d_in, const int* in_sizes, int n_in,
                              void* d_out, int out_size, void* d_ws, size_t ws_size,
                              hipStream_t stream) {
    const float* scores = (const float*)d_in[0];
    const int*   labels = (const int*)d_in[1];
    float* ws  = (float*)d_ws;
    float* out = (float*)d_out;

    hipMemsetAsync(ws + ROWSUM_OFF, 0, ZERO_FLOATS * sizeof(float), stream);
    gather_pass<<<QN / 256, 256, 0, stream>>>(scores, labels, ws);
    main_pass<<<NB, TB, 0, stream>>>(scores, ws);
    reduce_pass<<<192, 256, 0, stream>>>(ws);
    final_pass<<<1, 256, 0, stream>>>(ws, out);
}

// Round 7
// 383.097 us; speedup vs baseline: 1.2920x; 1.0112x over previous
//
#include <hip/hip_runtime.h>

// clip_nce: Q=16384 queries, V=4096 videos, scores [Q,V] fp32, labels [Q] int.
// R11 -> R12: revert nt colcomp stores (R11: +15us — writeback is triggered by
// the read stream's L3 allocations, not our stores; nt stores just pushed
// reduce's colcomp re-read to HBM). Sweep loop FROZEN (R8/R3 form: contiguous
// 128KB/block, nt loads, in-loop shfl+atomic). ONE package: kill the auxiliary
// launch tax WITHOUT touching the sweep loop.
//  - gather fused as EXTRA BLOCKS (b>=2048) of main_pass: block-uniform branch,
//    sweep blocks' codegen untouched; gather latency overlaps under the sweep.
//    (R6's failure was per-ITERATION label s_load inside the hot loop — not this.)
//  - reduce+final merged via last-block ticket (threadfence + atomic readback,
//    correctness-proven in R6's run).
// Launches 5 -> 3.

#define QN 16384
#define VN 4096
#define NB 2048
#define TB 256
#define ITERS 32                          // 8 rows * 4 quarter-rows
#define F4_PER_BLOCK 8192                 // 128 KB contiguous per block

typedef float f32x4 __attribute__((ext_vector_type(4)));

// workspace layout in floats (~33.5 MiB):
#define COLCOMP_OFF 0                     // NB*4096 column partials (full row per block)
#define ROWSUM_OFF  (NB * 4096)           // QN: sum exp per row (global atomics)
#define NOMSUM_OFF  (ROWSUM_OFF + QN)     // VN: sum exp(s) per label
#define COLSUM_OFF  (NOMSUM_OFF + VN)     // VN: column exp-sums (natural order)
#define ACC_OFF     (COLSUM_OFF + VN)     // [0]=sum log rowsum, [1]=sum s
#define TICKET_OFF  (ACC_OFF + 4)         // int ticket slot (zeroed by memset)
#define ZERO_FLOATS (QN + VN + VN + 8)    // rowsum + nomsum + colsum + acc/ticket

// Contiguous dense sweep, NON-TEMPORAL loads, in-loop reduce (proven shape).
// Blocks [0,NB): sweep. Block b reads f4 [b*8192,(b+1)*8192) in 32 steps.
//   iter k: f4 = b*8192 + k*256 + t; row = b*8 + (k>>2); col = (k&3)*1024 + t*4 + j
// Blocks [NB,NB+64): fused gather — 16384 label gathers + nomsum + sum(s).
__global__ __launch_bounds__(256, 8) void main_pass(const float* __restrict__ scores,
                                                    const int* __restrict__ labels,
                                                    float* __restrict__ ws) {
    float* rowsum  = ws + ROWSUM_OFF;
    float* nomsum  = ws + NOMSUM_OFF;
    float* colcomp = ws + COLCOMP_OFF;
    float* acc     = ws + ACC_OFF;
    const int tid  = threadIdx.x;
    const int b    = blockIdx.x;
    const int lane = tid & 63;

    if (b >= NB) {   // ---- gather role (block-uniform branch) ----
        const int i = (b - NB) * 256 + tid;
        const int lab = labels[i];
        const float s = scores[(size_t)i * VN + lab];
        unsafeAtomicAdd(&nomsum[lab], __expf(s));
        float v = s;
#pragma unroll
        for (int off = 32; off >= 1; off >>= 1)
            v += __shfl_down(v, off);
        if (lane == 0) unsafeAtomicAdd(&acc[1], v);
        return;
    }

    // ---- sweep role: loop body identical to R8/R3 ----
    const f32x4* sp = reinterpret_cast<const f32x4*>(scores);
    const size_t base = (size_t)b * F4_PER_BLOCK + tid;

    float c00=0.f,c01=0.f,c02=0.f,c03=0.f;   // q=0
    float c10=0.f,c11=0.f,c12=0.f,c13=0.f;   // q=1
    float c20=0.f,c21=0.f,c22=0.f,c23=0.f;   // q=2
    float c30=0.f,c31=0.f,c32=0.f,c33=0.f;   // q=3

#pragma unroll 8
    for (int k = 0; k < ITERS; ++k) {
        f32x4 x = __builtin_nontemporal_load(&sp[base + k * 256]);
        float e0 = __expf(x.x), e1 = __expf(x.y);
        float e2 = __expf(x.z), e3 = __expf(x.w);
        // q = k&3 is a compile-time constant inside the unrolled body
        switch (k & 3) {
            case 0: c00 += e0; c01 += e1; c02 += e2; c03 += e3; break;
            case 1: c10 += e0; c11 += e1; c12 += e2; c13 += e3; break;
            case 2: c20 += e0; c21 += e1; c22 += e2; c23 += e3; break;
            case 3: c30 += e0; c31 += e1; c32 += e2; c33 += e3; break;
        }
        float rp = (e0 + e1) + (e2 + e3);
#pragma unroll
        for (int off = 32; off >= 1; off >>= 1)
            rp += __shfl_down(rp, off);
        if (lane == 0)   // 16 atomics per row address total (4 waves x 4 quarter-iters)
            unsafeAtomicAdd(&rowsum[b * 8 + (k >> 2)], rp);
    }

    // col partials: one full 4096-wide row of partials, coalesced, PLAIN stores
    // (allocate -> reduce pass hits them in L2/L3).
    f32x4* cc = reinterpret_cast<f32x4*>(colcomp + (size_t)b * 4096);
    f32x4 o;
    o.x=c00; o.y=c01; o.z=c02; o.w=c03; cc[0 * 256 + tid] = o;
    o.x=c10; o.y=c11; o.z=c12; o.w=c13; cc[1 * 256 + tid] = o;
    o.x=c20; o.y=c21; o.z=c22; o.w=c23; cc[2 * 256 + tid] = o;
    o.x=c30; o.y=c31; o.z=c32; o.w=c33; cc[3 * 256 + tid] = o;
}

// blocks [0,128): colsum from partials (32 MiB read, coalesced).
//   block = mg*16 + cb: b-range mg (8 groups of 256 blocks), col-chunk cb (16 x 256 cols)
// blocks [128,192): sum log rowsum -> acc[0]
// last block through the ticket computes the final scalar (fused final_pass).
__global__ __launch_bounds__(256) void reduce_final(float* __restrict__ ws,
                                                    float* __restrict__ out) {
    const float* colcomp = ws + COLCOMP_OFF;
    const float* rowsum  = ws + ROWSUM_OFF;
    float* colsum = ws + COLSUM_OFF;
    float* nomsum = ws + NOMSUM_OFF;
    float* acc    = ws + ACC_OFF;
    int* ticket   = reinterpret_cast<int*>(ws + TICKET_OFF);
    const int tid = threadIdx.x;

    if (blockIdx.x < 128) {
        const int mg = blockIdx.x >> 4;          // block-range group 0..7
        const int cb = blockIdx.x & 15;          // 256-col chunk 0..15
        const int c  = cb * 256 + tid;           // column 0..4095
        float sum = 0.0f;
#pragma unroll 4
        for (int m = mg * 256; m < mg * 256 + 256; ++m)
            sum += colcomp[(size_t)m * 4096 + c];
        unsafeAtomicAdd(&colsum[c], sum);
    } else {
        const int idx = (blockIdx.x - 128) * 256 + tid;
        float v = __logf(rowsum[idx]);
#pragma unroll
        for (int off = 32; off >= 1; off >>= 1)
            v += __shfl_down(v, off);
        if ((tid & 63) == 0) unsafeAtomicAdd(&acc[0], v);
    }

    // last-block ticket: the fence orders this block's device-scope atomics;
    // the winner sees all 192 blocks' contributions via atomic readback.
    __threadfence();
    __shared__ int amLast;
    if (tid == 0) amLast = (atomicAdd(ticket, 1) == 191);
    __syncthreads();
    if (!amLast) return;

    float local = 0.0f;
    for (int c = tid; c < VN; c += 256) {
        // atomic readback (returns old value) -> coherent view of all XCDs'
        // atomics regardless of local L2 state.
        const float cs = atomicAdd(&colsum[c], 0.0f);
        const float ns = atomicAdd(&nomsum[c], 0.0f);
        local += __logf(cs) - __logf(ns);
    }
#pragma unroll
    for (int off = 32; off >= 1; off >>= 1)
        local += __shfl_down(local, off);
    __shared__ float red[4];
    const int wid = tid >> 6, lane = tid & 63;
    if (lane == 0) red[wid] = local;
    __syncthreads();
    if (tid == 0) {
        const float a0 = atomicAdd(&acc[0], 0.0f);
        const float a1 = atomicAdd(&acc[1], 0.0f);
        const float v2t = (red[0] + red[1]) + (red[2] + red[3]);
        // mean(log rowsum - s) + mean(log colsum - log nomsum)
        out[0] = (a0 - a1) * (1.0f / QN) + v2t * (1.0f / VN);
    }
}

extern "C" void kernel_launch(void* const* d_in, const int* in_sizes, int n_in,
                              void* d_out, int out_size, void* d_ws, size_t ws_size,
                              hipStream_t stream) {
    const float* scores = (const float*)d_in[0];
    const int*   labels = (const int*)d_in[1];
    float* ws  = (float*)d_ws;
    float* out = (float*)d_out;

    hipMemsetAsync(ws + ROWSUM_OFF, 0, ZERO_FLOATS * sizeof(float), stream);
    main_pass<<<NB + QN / 256, TB, 0, stream>>>(scores, labels, ws);
    reduce_final<<<192, 256, 0, stream>>>(ws, out);
}